// Round 7
// baseline (1159.475 us; speedup 1.0000x reference)
//
#include <hip/hip_runtime.h>

#define BB 8
#define NN 2048
#define KNN 20
#define NPOS (BB*NN)          // 16384 points
#define NEDGE (NPOS*KNN)      // 327680 edge positions

typedef _Float16 f16x8 __attribute__((ext_vector_type(8)));
typedef __fp16 fp16x2 __attribute__((ext_vector_type(2)));
typedef float f32x4 __attribute__((ext_vector_type(4)));

union H16 { _Float16 h; unsigned short u; };
__device__ __forceinline__ unsigned short f2h(float f){ H16 x; x.h = (_Float16)f; return x.u; }
__device__ __forceinline__ float h2f(unsigned short u){ H16 x; x.u = u; return (float)x.h; }
__device__ __forceinline__ unsigned pkrtz(float a, float b){
  union { fp16x2 h; unsigned u; } c; c.h = __builtin_amdgcn_cvt_pkrtz(a, b); return c.u;
}

// ---------- 1. de-mean ----------
__global__ __launch_bounds__(256) void k_demean(const float* __restrict__ pts, float* __restrict__ xt){
  int b = blockIdx.x / 3, d = blockIdx.x % 3;
  const float* row = pts + (size_t)(b*3 + d)*NN;
  __shared__ float red[256];
  int t = threadIdx.x;
  float s = 0.f;
  for (int n = t; n < NN; n += 256) s += row[n];
  red[t] = s; __syncthreads();
  for (int w = 128; w > 0; w >>= 1){ if (t < w) red[t] += red[t+w]; __syncthreads(); }
  float mean = red[0] * (1.0f/NN);
  for (int n = t; n < NN; n += 256) xt[(size_t)(b*NN + n)*4 + d] = row[n] - mean;
}

// ---------- 2. knn ----------
__global__ __launch_bounds__(256) void k_knn(const float* __restrict__ xt, unsigned short* __restrict__ idxo){
  __shared__ float4 xl[NN];
  __shared__ float tv[KNN][256];
  __shared__ unsigned short ti[KNN][256];
  int b = blockIdx.x >> 6;
  int pbase = (blockIdx.x & 63) * 32;
  int t = threadIdx.x;
  const float4* xb = (const float4*)xt + (size_t)b*NN;
  for (int m = t; m < NN; m += 256){
    float4 v = xb[m];
    v.w = v.x*v.x + v.y*v.y + v.z*v.z;
    xl[m] = v;
  }
  __syncthreads();
  int pl = t >> 3, g = t & 7;
  int n = pbase + pl;
  float4 xn = xl[n];
  float sqn = xn.w;
  for (int j = 0; j < 20; ++j){
    int m = g + (j << 3);
    float4 xm = xl[m];
    float nd = 2.f*(xn.x*xm.x + xn.y*xm.y + xn.z*xm.z) - sqn - xm.w;
    tv[j][t] = nd; ti[j][t] = (unsigned short)m;
  }
  float curmin = tv[0][t]; int minslot = 0;
  #pragma unroll
  for (int j = 1; j < 20; ++j){ float v = tv[j][t]; if (v < curmin){ curmin = v; minslot = j; } }
  for (int j = 20; j < 256; ++j){
    int m = g + (j << 3);
    float4 xm = xl[m];
    float nd = 2.f*(xn.x*xm.x + xn.y*xm.y + xn.z*xm.z) - sqn - xm.w;
    if (nd > curmin){
      tv[minslot][t] = nd; ti[minslot][t] = (unsigned short)m;
      curmin = tv[0][t]; minslot = 0;
      #pragma unroll
      for (int u = 1; u < 20; ++u){ float vv = tv[u][t]; if (vv < curmin){ curmin = vv; minslot = u; } }
    }
  }
  __syncthreads();
  for (int s = 4; s; s >>= 1){
    if (g < s){
      int src = t + s;
      for (int jj = 0; jj < 20; ++jj){
        float v = tv[jj][src];
        if (v > curmin){
          unsigned short mi = ti[jj][src];
          tv[minslot][t] = v; ti[minslot][t] = mi;
          curmin = tv[0][t]; minslot = 0;
          #pragma unroll
          for (int u = 1; u < 20; ++u){ float vv = tv[u][t]; if (vv < curmin){ curmin = vv; minslot = u; } }
        }
      }
    }
    __syncthreads();
  }
  if (g == 0){
    unsigned short* op = idxo + (size_t)(b*NN + pbase + pl)*KNN;
    #pragma unroll
    for (int j = 0; j < 20; ++j) op[j] = ti[j][t];
  }
}

// ---------- 3. weight prep f32->f16 [w2|w3|w4|w5] ----------
__global__ __launch_bounds__(256) void k_wprep(const float* __restrict__ W2, const float* __restrict__ W3,
    const float* __restrict__ W4, const float* __restrict__ W5, unsigned short* __restrict__ wh){
  int i = blockIdx.x*256 + threadIdx.x;
  float v;
  if (i < 4096) v = W2[i];
  else if (i < 12288) v = W3[i-4096];
  else if (i < 45056) v = W4[i-12288];
  else v = W5[i-45056];
  wh[i] = f2h(v);
}

// ---------- 4. conv1 ----------
__global__ __launch_bounds__(256) void k_conv1(const float* __restrict__ xt, const unsigned short* __restrict__ idx,
    const float* __restrict__ W1, unsigned short* __restrict__ y1){
  __shared__ float Wl[64*6];
  int t = threadIdx.x;
  for (int i = t; i < 384; i += 256) Wl[i] = W1[i];
  __syncthreads();
  int e = blockIdx.x*256 + t;
  int p = e / KNN;
  int b = p >> 11;
  int n = p & (NN-1);
  int nb = idx[e];
  const float4* xb = (const float4*)xt + (size_t)b*NN;
  float4 xnb = xb[nb], xcn = xb[n];
  unsigned short* yo = y1 + (size_t)e*64;
  #pragma unroll
  for (int o = 0; o < 64; o += 8){
    unsigned pk[4];
    #pragma unroll
    for (int q = 0; q < 4; ++q){
      const float* wa = &Wl[(o+2*q)*6];
      const float* wb = &Wl[(o+2*q+1)*6];
      float va = wa[0]*xnb.x + wa[1]*xnb.y + wa[2]*xnb.z + wa[3]*xcn.x + wa[4]*xcn.y + wa[5]*xcn.z;
      float vb = wb[0]*xnb.x + wb[1]*xnb.y + wb[2]*xnb.z + wb[3]*xcn.x + wb[4]*xcn.y + wb[5]*xcn.z;
      pk[q] = pkrtz(va, vb);
    }
    uint4 u; u.x = pk[0]; u.y = pk[1]; u.z = pk[2]; u.w = pk[3];
    *reinterpret_cast<uint4*>(yo + o) = u;
  }
}

// ---------- 5. stats for y1 (direct), 64-sharded ----------
__global__ __launch_bounds__(256) void k_stats1(const unsigned short* __restrict__ y, float* __restrict__ st){
  int t = threadIdx.x;
  int c = t & 63, ro = t >> 6;
  float s = 0.f, q = 0.f;
  for (int rb = blockIdx.x; rb < NEDGE/4; rb += gridDim.x){
    float v = h2f(y[(size_t)(rb*4 + ro)*64 + c]);
    s += v; q += v*v;
  }
  __shared__ float red[256];
  red[t] = s; __syncthreads();
  if (t < 64){ for (int g = 1; g < 4; ++g) s += red[t + g*64]; }
  __syncthreads(); red[t] = q; __syncthreads();
  if (t < 64){
    for (int g = 1; g < 4; ++g) q += red[t + g*64];
    int shard = blockIdx.x & 63;
    atomicAdd(&st[c*64 + shard], s);
    atomicAdd(&st[64*64 + c*64 + shard], q);
  }
}

// ---------- 5b. stats for y5 (slabbed [8][NPOS][64] f16) ----------
__global__ __launch_bounds__(256) void k_stats512(const unsigned short* __restrict__ y, float* __restrict__ st){
  int t = threadIdx.x;
  int slab = t >> 5, cc0 = (t & 31)*2;
  int c0 = slab*64 + cc0;
  const unsigned short* yb = y + (size_t)slab*NPOS*64 + cc0;
  float s0=0.f,q0=0.f,s1=0.f,q1=0.f;
  for (int rw = blockIdx.x; rw < NPOS; rw += gridDim.x){
    unsigned u = *reinterpret_cast<const unsigned*>(yb + (size_t)rw*64);
    float v0 = h2f((unsigned short)(u & 0xffffu)), v1 = h2f((unsigned short)(u >> 16));
    s0 += v0; q0 += v0*v0; s1 += v1; q1 += v1*v1;
  }
  int shard = blockIdx.x & 63;
  atomicAdd(&st[(size_t)c0*64 + shard], s0);
  atomicAdd(&st[(size_t)(512 + c0)*64 + shard], q0);
  atomicAdd(&st[(size_t)(c0+1)*64 + shard], s1);
  atomicAdd(&st[(size_t)(512 + c0+1)*64 + shard], q1);
}

// ---------- 6. finalize BN from sharded stats -> ac f32 + aH f16 ----------
__global__ void k_fin(const float* __restrict__ st, const float* __restrict__ gw, const float* __restrict__ bw,
                      float* __restrict__ act, unsigned short* __restrict__ actH, int C, float inv_n){
  int c = threadIdx.x;
  if (c >= C) return;
  float s = 0.f, q = 0.f;
  for (int i = 0; i < 64; ++i){ s += st[c*64 + i]; q += st[(size_t)C*64 + c*64 + i]; }
  float mean = s*inv_n;
  float var = q*inv_n - mean*mean;
  float sc = gw[c] * rsqrtf(var + 1e-5f);
  float sh = bw[c] - mean*sc;
  act[2*c] = sc; act[2*c+1] = sh;
  actH[c] = f2h(sc); actH[C + c] = f2h(sh);
}

// ---------- 7. layer-1 max pool ----------
__global__ __launch_bounds__(256) void k_max64(const unsigned short* __restrict__ y, const float* __restrict__ actp,
    unsigned short* __restrict__ xc, int xcoff){
  int gidx = blockIdx.x*256 + threadIdx.x;
  int q = gidx >> 5, cp = gidx & 31;
  int c = cp*2;
  float sc0 = actp[2*c],   sh0 = actp[2*c+1];
  float sc1 = actp[2*c+2], sh1 = actp[2*c+3];
  const unsigned* base = reinterpret_cast<const unsigned*>(y + (size_t)q*KNN*64 + c);
  float m0 = 0.f, m1 = 0.f;
  #pragma unroll
  for (int j = 0; j < KNN; ++j){
    unsigned v = base[(size_t)j*32];
    m0 = fmaxf(m0, sc0*h2f((unsigned short)(v & 0xffffu)) + sh0);
    m1 = fmaxf(m1, sc1*h2f((unsigned short)(v >> 16)) + sh1);
  }
  *reinterpret_cast<unsigned*>(xc + (size_t)q*512 + xcoff + c) = pkrtz(m0, m1);
}

// ---------- 8. Gram: G = sum_e a_e a_e^T (+colsum), a = (FOLD? act(y): y) f16 ----------
template<int C, bool FOLD>
__global__ __launch_bounds__(256, 3) void k_gram(const unsigned short* __restrict__ inA,
    const unsigned short* __restrict__ inB, const unsigned short* __restrict__ aH,
    float* __restrict__ G, float* __restrict__ cs, int nchunks){
  constexpr int NFR = C/16;
  constexpr int RI = (C == 64) ? 1 : 2;
  __shared__ unsigned short st[32][C + 8];
  int t = threadIdx.x, lane = t & 63, w = t >> 6, g = lane >> 4, r = lane & 15;
  int srow = t >> 3, scg = t & 7;
  const f16x8 zf = (f16x8)(_Float16)0.f;
  f16x8 fs, fh;
  if constexpr (FOLD){
    fs = *reinterpret_cast<const f16x8*>(aH + scg*8);
    fh = *reinterpret_cast<const f16x8*>(aH + C + scg*8);
  }
  f32x4 acc[RI][NFR];
  #pragma unroll
  for (int i = 0; i < RI; ++i)
    #pragma unroll
    for (int j = 0; j < NFR; ++j) acc[i][j] = 0.f;
  float csf[NFR] = {};
  for (int ch = blockIdx.x; ch < nchunks; ch += gridDim.x){
    int e0 = ch*32;
    if constexpr (C == 64){
      f16x8 v = *reinterpret_cast<const f16x8*>(inA + (size_t)(e0+srow)*64 + scg*8);
      if constexpr (FOLD) v = __builtin_elementwise_max(v*fs + fh, zf);
      *reinterpret_cast<f16x8*>(&st[srow][scg*8]) = v;
    } else {
      const unsigned short* base = (scg < 4) ? (inA + (size_t)(e0+srow)*64 + scg*16)
                                             : (inB + (size_t)(e0+srow)*64 + (scg-4)*16);
      f16x8 v0 = *reinterpret_cast<const f16x8*>(base);
      f16x8 v1 = *reinterpret_cast<const f16x8*>(base + 8);
      *reinterpret_cast<f16x8*>(&st[srow][scg*16]) = v0;
      *reinterpret_cast<f16x8*>(&st[srow][scg*16 + 8]) = v1;
    }
    __syncthreads();
    f16x8 fr[NFR];
    #pragma unroll
    for (int f = 0; f < NFR; ++f)
      #pragma unroll
      for (int jj = 0; jj < 8; ++jj){
        H16 x; x.u = st[8*g + jj][16*f + r]; fr[f][jj] = x.h;
      }
    if (w == 0){
      #pragma unroll
      for (int f = 0; f < NFR; ++f)
        #pragma unroll
        for (int jj = 0; jj < 8; ++jj) csf[f] += (float)fr[f][jj];
    }
    #pragma unroll
    for (int i = 0; i < RI; ++i)
      #pragma unroll
      for (int j = 0; j < NFR; ++j)
        acc[i][j] = __builtin_amdgcn_mfma_f32_16x16x32_f16(fr[RI*w + i], fr[j], acc[i][j], 0, 0, 0);
    __syncthreads();
  }
  #pragma unroll
  for (int i = 0; i < RI; ++i){
    int gr = 16*(RI*w + i) + 4*g;
    #pragma unroll
    for (int j = 0; j < NFR; ++j)
      #pragma unroll
      for (int p = 0; p < 4; ++p)
        atomicAdd(&G[(size_t)(gr + p)*C + 16*j + r], acc[i][j][p]);
  }
  if (w == 0){
    #pragma unroll
    for (int f = 0; f < NFR; ++f){
      float v = csf[f];
      v += __shfl_xor(v, 16);
      v += __shfl_xor(v, 32);
      if (lane < 16) atomicAdd(&cs[16*f + lane], v);
    }
  }
}

// ---------- 9. BN stats of NEXT layer from Gram + weights (linearity) ----------
template<int CIN, int COUT>
__global__ void k_fing(const float* __restrict__ G, const float* __restrict__ cs,
    const unsigned short* __restrict__ whp, const float* __restrict__ gw, const float* __restrict__ bw,
    float* __restrict__ ac, unsigned short* __restrict__ aH, float inv_n){
  __shared__ float red[CIN], red2[CIN];
  int o = blockIdx.x, i = threadIdx.x;
  float wi = h2f(whp[(size_t)o*CIN + i]);
  float v = 0.f;
  for (int j = 0; j < CIN; ++j) v += G[(size_t)i*CIN + j] * h2f(whp[(size_t)o*CIN + j]);
  red[i] = wi*v; red2[i] = wi*cs[i];
  __syncthreads();
  for (int s = CIN/2; s > 0; s >>= 1){
    if (i < s){ red[i] += red[i+s]; red2[i] += red2[i+s]; }
    __syncthreads();
  }
  if (i == 0){
    float mean = red2[0]*inv_n;
    float var = red[0]*inv_n - mean*mean;
    float sc = gw[o]*rsqrtf(var + 1e-5f);
    float sh = bw[o] - mean*sc;
    ac[2*o] = sc; ac[2*o+1] = sh;
    aH[o] = f2h(sc); aH[COUT + o] = f2h(sh);
  }
}

// ---------- 10. conv: post-act output, optional input fold / store / window max-pool ----------
// acc[m][n]: och = o*64+16n+4g+r (rows), pos = (m?16:0)+r16 (cols). Window-aligned when POOL.
template<int CIN, int COUT, bool INFOLD, bool OUTACT, bool POOL, bool STORE>
__global__ __launch_bounds__(256, 3) void k_cpost(
    const unsigned short* __restrict__ inA, const unsigned short* __restrict__ inB,
    const unsigned short* __restrict__ Wh, const unsigned short* __restrict__ aHin,
    const float* __restrict__ acOut, unsigned short* __restrict__ out, size_t slabStride,
    unsigned short* __restrict__ xc, int coff, int NT){
  constexpr int NKC = CIN/32;
  constexpr int NO = COUT/64;
  constexpr int LIM = POOL ? 20 : 32;
  constexpr int RS = (CIN == 128) ? 64 : CIN;    // row stride per slab
  __shared__ unsigned short Tw[4][32][68];
  int t = threadIdx.x, lane = t & 63, w = t >> 6, g = lane >> 4, r16 = lane & 15;
  const f16x8 zf = (f16x8)(_Float16)0.f;
  f16x8 fs[INFOLD ? NKC : 1], fh[INFOLD ? NKC : 1];
  if constexpr (INFOLD){
    #pragma unroll
    for (int kc = 0; kc < NKC; ++kc){
      fs[kc] = *reinterpret_cast<const f16x8*>(aHin + kc*32 + g*8);
      fh[kc] = *reinterpret_cast<const f16x8*>(aHin + CIN + kc*32 + g*8);
    }
  }
  int wid = blockIdx.x*4 + w;
  int nw = gridDim.x*4;
  for (int task = wid; task < NT; task += nw){
    int p0 = task * (POOL ? 20 : 32);
    int ra = p0 + r16;
    int rb = POOL ? (p0 + 16 + (r16 < 4 ? r16 : 3)) : (p0 + 16 + r16);
    f16x8 A0[(CIN <= 128) ? NKC : 1], A1[(CIN <= 128) ? NKC : 1];
    if constexpr (CIN <= 128){
      #pragma unroll
      for (int kc = 0; kc < NKC; ++kc){
        const unsigned short* ab; int kl;
        if constexpr (CIN == 128){ ab = (kc < NKC/2) ? inA : inB; kl = kc & (NKC/2 - 1); }
        else { ab = inA; kl = kc; }
        f16x8 a0 = *reinterpret_cast<const f16x8*>(ab + (size_t)ra*RS + kl*32 + g*8);
        f16x8 a1 = *reinterpret_cast<const f16x8*>(ab + (size_t)rb*RS + kl*32 + g*8);
        if constexpr (INFOLD){
          a0 = __builtin_elementwise_max(a0*fs[kc] + fh[kc], zf);
          a1 = __builtin_elementwise_max(a1*fs[kc] + fh[kc], zf);
        }
        A0[kc] = a0; A1[kc] = a1;
      }
    }
    #pragma unroll 1
    for (int o = 0; o < NO; ++o){
      f32x4 acc[2][4];
      #pragma unroll
      for (int m = 0; m < 2; ++m)
        #pragma unroll
        for (int n = 0; n < 4; ++n) acc[m][n] = 0.f;
      #pragma unroll 4
      for (int kc = 0; kc < NKC; ++kc){
        f16x8 a0, a1;
        if constexpr (CIN <= 128){ a0 = A0[kc]; a1 = A1[kc]; }
        else {
          a0 = *reinterpret_cast<const f16x8*>(inA + (size_t)ra*CIN + kc*32 + g*8);
          a1 = *reinterpret_cast<const f16x8*>(inA + (size_t)rb*CIN + kc*32 + g*8);
        }
        #pragma unroll
        for (int n = 0; n < 4; ++n){
          f16x8 bv = *reinterpret_cast<const f16x8*>(Wh + (size_t)(o*64 + 16*n + r16)*CIN + kc*32 + g*8);
          acc[0][n] = __builtin_amdgcn_mfma_f32_16x16x32_f16(bv, a0, acc[0][n], 0, 0, 0);
          acc[1][n] = __builtin_amdgcn_mfma_f32_16x16x32_f16(bv, a1, acc[1][n], 0, 0, 0);
        }
      }
      if constexpr (OUTACT){
        #pragma unroll
        for (int n = 0; n < 4; ++n){
          const float4* ap = reinterpret_cast<const float4*>(acOut + 2*(o*64 + 16*n + 4*g));
          float4 q0 = ap[0], q1 = ap[1];
          #pragma unroll
          for (int m = 0; m < 2; ++m){
            acc[m][n][0] = fmaxf(0.f, acc[m][n][0]*q0.x + q0.y);
            acc[m][n][1] = fmaxf(0.f, acc[m][n][1]*q0.z + q0.w);
            acc[m][n][2] = fmaxf(0.f, acc[m][n][2]*q1.x + q1.y);
            acc[m][n][3] = fmaxf(0.f, acc[m][n][3]*q1.z + q1.w);
          }
        }
      }
      if constexpr (STORE){
        #pragma unroll
        for (int m = 0; m < 2; ++m)
          #pragma unroll
          for (int n = 0; n < 4; ++n){
            uint2 d;
            d.x = pkrtz(acc[m][n][0], acc[m][n][1]);
            d.y = pkrtz(acc[m][n][2], acc[m][n][3]);
            *reinterpret_cast<uint2*>(&Tw[w][16*m + r16][16*n + 4*g]) = d;
          }
        int pos = lane >> 1, chh = (lane & 1) * 32;
        if (pos < LIM){
          const unsigned short* rp = &Tw[w][pos][chh];
          uint2 d0 = *reinterpret_cast<const uint2*>(rp);
          uint2 d1 = *reinterpret_cast<const uint2*>(rp + 4);
          uint2 d2 = *reinterpret_cast<const uint2*>(rp + 8);
          uint2 d3 = *reinterpret_cast<const uint2*>(rp + 12);
          uint2 d4 = *reinterpret_cast<const uint2*>(rp + 16);
          uint2 d5 = *reinterpret_cast<const uint2*>(rp + 20);
          uint2 d6 = *reinterpret_cast<const uint2*>(rp + 24);
          uint2 d7 = *reinterpret_cast<const uint2*>(rp + 28);
          uint4* op = reinterpret_cast<uint4*>(out + (size_t)o*slabStride + ((size_t)(p0 + pos))*64 + chh);
          op[0] = make_uint4(d0.x, d0.y, d1.x, d1.y);
          op[1] = make_uint4(d2.x, d2.y, d3.x, d3.y);
          op[2] = make_uint4(d4.x, d4.y, d5.x, d5.y);
          op[3] = make_uint4(d6.x, d6.y, d7.x, d7.y);
        }
      }
      if constexpr (POOL){
        #pragma unroll
        for (int n = 0; n < 4; ++n){
          float vr[4];
          #pragma unroll
          for (int r = 0; r < 4; ++r){
            float v = fmaxf(acc[0][n][r], acc[1][n][r]);   // m=1 cols r16>=4 dup row19 (valid window row)
            v = fmaxf(v, __shfl_xor(v, 1));
            v = fmaxf(v, __shfl_xor(v, 2));
            v = fmaxf(v, __shfl_xor(v, 4));
            v = fmaxf(v, __shfl_xor(v, 8));
            vr[r] = v;
          }
          if (r16 == 0){
            uint2 u;
            u.x = pkrtz(vr[0], vr[1]);
            u.y = pkrtz(vr[2], vr[3]);
            *reinterpret_cast<uint2*>(xc + (size_t)task*512 + coff + o*64 + 16*n + 4*g) = u;
          }
        }
      }
    }
  }
}

// ---------- 11. final: bn5+relu on y5 slabs [8][NPOS][64] f16 -> out [b][512][n] f32 ----------
__global__ void k_out(const unsigned short* __restrict__ y5, const float* __restrict__ actp, float* __restrict__ out){
  __shared__ float tile[32][33];
  int b = blockIdx.z, n0 = blockIdx.x*32, c0 = blockIdx.y*32;
  int lx = threadIdx.x, ly = threadIdx.y;
  int slab = c0 >> 6, cin = (c0 & 63) + lx;
  float sc = actp[2*(c0+lx)], sh = actp[2*(c0+lx)+1];
  const unsigned short* yb = y5 + (size_t)slab*NPOS*64 + (size_t)(b*NN + n0)*64 + cin;
  for (int yy = ly; yy < 32; yy += 8)
    tile[yy][lx] = fmaxf(0.f, sc*h2f(yb[(size_t)yy*64]) + sh);
  __syncthreads();
  for (int yy = ly; yy < 32; yy += 8)
    out[((size_t)(b*512 + c0 + yy))*NN + n0 + lx] = tile[lx][yy];
}

// ---------- launch ----------
extern "C" void kernel_launch(void* const* d_in, const int* in_sizes, int n_in,
                              void* d_out, int out_size, void* d_ws, size_t ws_size,
                              hipStream_t stream){
  const float* pts = (const float*)d_in[0];
  const float* W1 = (const float*)d_in[1];
  const float* W2 = (const float*)d_in[2];
  const float* W3 = (const float*)d_in[3];
  const float* W4 = (const float*)d_in[4];
  const float* W5 = (const float*)d_in[5];
  const float* g1 = (const float*)d_in[6];  const float* b1 = (const float*)d_in[7];
  const float* g2 = (const float*)d_in[8];  const float* b2 = (const float*)d_in[9];
  const float* g3 = (const float*)d_in[10]; const float* b3 = (const float*)d_in[11];
  const float* g4 = (const float*)d_in[12]; const float* b4 = (const float*)d_in[13];
  const float* g5 = (const float*)d_in[14]; const float* b5 = (const float*)d_in[15];

  char* ws = (char*)d_ws;
  float*          xt    = (float*)(ws + 0);                      // 256 KB
  unsigned short* idxu  = (unsigned short*)(ws + 262144);        // 640 KB
  float*          stats = (float*)(ws + 917504);                 // 288 KB  (st1 + st5)
  float*          gbuf  = (float*)(ws + 1212416);                // ~100 KB (G1,G2,G3,cs1,cs2,cs3)
  float*          acts  = (float*)(ws + 1314816);                // 8 KB f32
  unsigned short* actsH = (unsigned short*)(ws + 1323008);       // 4 KB f16
  unsigned short* wh    = (unsigned short*)(ws + 1327104);       // 600 KB f16 weights
  // big buffers with overlays:
  unsigned short* y1  = (unsigned short*)(ws + 2097152);         // 40 MiB
  unsigned short* y3a = (unsigned short*)(ws + 2097152);         //   (overlays dead y1)
  unsigned short* y2p = (unsigned short*)(ws + 44040192);        // 40 MiB
  unsigned short* y5  = (unsigned short*)(ws + 44040192);        //   (overlays dead y2p, 16 MiB)
  unsigned short* y3b = (unsigned short*)(ws + 85983232);        // 40 MiB
  unsigned short* xc  = (unsigned short*)(ws + 127926272);       // 16 MiB -> end ~138 MiB
  float* out = (float*)d_out;

  unsigned short* w2h = wh;
  unsigned short* w3h = wh + 4096;
  unsigned short* w4h = wh + 12288;
  unsigned short* w5h = wh + 45056;

  float* st1 = stats;                 // 2*64*64 f32
  float* st5 = stats + 8192;          // 2*512*64 f32
  float* G1 = gbuf, *G2 = gbuf + 4096, *G3 = gbuf + 8192;
  float* cs1 = gbuf + 24576, *cs2 = gbuf + 24640, *cs3 = gbuf + 24704;
  float* ac1 = acts + 0,  *ac2 = acts + 128, *ac3 = acts + 256, *ac4 = acts + 512, *ac5 = acts + 1024;
  unsigned short* aH1 = actsH + 0,   *aH2 = actsH + 128, *aH3 = actsH + 256,
                * aH4 = actsH + 512, *aH5 = actsH + 1024;
  const size_t y3str = (size_t)(85983232 - 2097152) / 2;

  hipMemsetAsync(stats, 0, 294912, stream);
  hipMemsetAsync(gbuf, 0, 102400, stream);
  k_wprep<<<1200, 256, 0, stream>>>(W2, W3, W4, W5, wh);
  k_demean<<<24, 256, 0, stream>>>(pts, xt);
  k_knn<<<512, 256, 0, stream>>>(xt, idxu);
  k_conv1<<<NEDGE/256, 256, 0, stream>>>(xt, idxu, W1, y1);
  k_stats1<<<256, 256, 0, stream>>>(y1, st1);
  k_fin<<<1, 64, 0, stream>>>(st1, g1, b1, ac1, aH1, 64, 1.f/NEDGE);
  k_max64<<<NPOS*32/256, 256, 0, stream>>>(y1, ac1, xc, 0);
  k_gram<64, true><<<320, 256, 0, stream>>>(y1, nullptr, aH1, G1, cs1, NEDGE/32);
  k_fing<64, 64><<<64, 64, 0, stream>>>(G1, cs1, w2h, g2, b2, ac2, aH2, 1.f/NEDGE);
  k_cpost<64, 64, true, true, true, true><<<1024, 256, 0, stream>>>(
      y1, nullptr, w2h, aH1, ac2, y2p, 0, xc, 64, NPOS);
  k_gram<64, false><<<320, 256, 0, stream>>>(y2p, nullptr, nullptr, G2, cs2, NEDGE/32);
  k_fing<64, 128><<<128, 64, 0, stream>>>(G2, cs2, w3h, g3, b3, ac3, aH3, 1.f/NEDGE);
  k_cpost<64, 128, false, true, true, true><<<1024, 256, 0, stream>>>(
      y2p, nullptr, w3h, nullptr, ac3, y3a, y3str, xc, 128, NPOS);
  k_gram<128, false><<<320, 256, 0, stream>>>(y3a, y3b, nullptr, G3, cs3, NEDGE/32);
  k_fing<128, 256><<<256, 128, 0, stream>>>(G3, cs3, w4h, g4, b4, ac4, aH4, 1.f/NEDGE);
  k_cpost<128, 256, false, true, true, false><<<1024, 256, 0, stream>>>(
      y3a, y3b, w4h, nullptr, ac4, nullptr, 0, xc, 256, NPOS);
  k_cpost<512, 512, false, false, false, true><<<128, 256, 0, stream>>>(
      xc, nullptr, w5h, nullptr, nullptr, y5, (size_t)NPOS*64, nullptr, 0, NPOS/32);
  k_stats512<<<256, 256, 0, stream>>>(y5, st5);
  k_fin<<<1, 512, 0, stream>>>(st5, g5, b5, ac5, aH5, 512, 1.f/NPOS);
  k_out<<<dim3(NN/32, 16, BB), dim3(32, 8), 0, stream>>>(y5, ac5, out);
}

// Round 8
// 987.709 us; speedup vs baseline: 1.1739x; 1.1739x over previous
//
#include <hip/hip_runtime.h>

#define BB 8
#define NN 2048
#define KNN 20
#define NPOS (BB*NN)          // 16384 points
#define NEDGE (NPOS*KNN)      // 327680 edge positions

typedef _Float16 f16x8 __attribute__((ext_vector_type(8)));
typedef _Float16 f16x4 __attribute__((ext_vector_type(4)));
typedef __fp16 fp16x2 __attribute__((ext_vector_type(2)));
typedef float f32x4 __attribute__((ext_vector_type(4)));

union H16 { _Float16 h; unsigned short u; };
__device__ __forceinline__ unsigned short f2h(float f){ H16 x; x.h = (_Float16)f; return x.u; }
__device__ __forceinline__ float h2f(unsigned short u){ H16 x; x.u = u; return (float)x.h; }
__device__ __forceinline__ unsigned pkrtz(float a, float b){
  union { fp16x2 h; unsigned u; } c; c.h = __builtin_amdgcn_cvt_pkrtz(a, b); return c.u;
}

// ---------- 1. de-mean ----------
__global__ __launch_bounds__(256) void k_demean(const float* __restrict__ pts, float* __restrict__ xt){
  int b = blockIdx.x / 3, d = blockIdx.x % 3;
  const float* row = pts + (size_t)(b*3 + d)*NN;
  __shared__ float red[256];
  int t = threadIdx.x;
  float s = 0.f;
  for (int n = t; n < NN; n += 256) s += row[n];
  red[t] = s; __syncthreads();
  for (int w = 128; w > 0; w >>= 1){ if (t < w) red[t] += red[t+w]; __syncthreads(); }
  float mean = red[0] * (1.0f/NN);
  for (int n = t; n < NN; n += 256) xt[(size_t)(b*NN + n)*4 + d] = row[n] - mean;
}

// ---------- 2. knn ----------
__global__ __launch_bounds__(256) void k_knn(const float* __restrict__ xt, unsigned short* __restrict__ idxo){
  __shared__ float4 xl[NN];
  __shared__ float tv[KNN][256];
  __shared__ unsigned short ti[KNN][256];
  int b = blockIdx.x >> 6;
  int pbase = (blockIdx.x & 63) * 32;
  int t = threadIdx.x;
  const float4* xb = (const float4*)xt + (size_t)b*NN;
  for (int m = t; m < NN; m += 256){
    float4 v = xb[m];
    v.w = v.x*v.x + v.y*v.y + v.z*v.z;
    xl[m] = v;
  }
  __syncthreads();
  int pl = t >> 3, g = t & 7;
  int n = pbase + pl;
  float4 xn = xl[n];
  float sqn = xn.w;
  for (int j = 0; j < 20; ++j){
    int m = g + (j << 3);
    float4 xm = xl[m];
    float nd = 2.f*(xn.x*xm.x + xn.y*xm.y + xn.z*xm.z) - sqn - xm.w;
    tv[j][t] = nd; ti[j][t] = (unsigned short)m;
  }
  float curmin = tv[0][t]; int minslot = 0;
  #pragma unroll
  for (int j = 1; j < 20; ++j){ float v = tv[j][t]; if (v < curmin){ curmin = v; minslot = j; } }
  for (int j = 20; j < 256; ++j){
    int m = g + (j << 3);
    float4 xm = xl[m];
    float nd = 2.f*(xn.x*xm.x + xn.y*xm.y + xn.z*xm.z) - sqn - xm.w;
    if (nd > curmin){
      tv[minslot][t] = nd; ti[minslot][t] = (unsigned short)m;
      curmin = tv[0][t]; minslot = 0;
      #pragma unroll
      for (int u = 1; u < 20; ++u){ float vv = tv[u][t]; if (vv < curmin){ curmin = vv; minslot = u; } }
    }
  }
  __syncthreads();
  for (int s = 4; s; s >>= 1){
    if (g < s){
      int src = t + s;
      for (int jj = 0; jj < 20; ++jj){
        float v = tv[jj][src];
        if (v > curmin){
          unsigned short mi = ti[jj][src];
          tv[minslot][t] = v; ti[minslot][t] = mi;
          curmin = tv[0][t]; minslot = 0;
          #pragma unroll
          for (int u = 1; u < 20; ++u){ float vv = tv[u][t]; if (vv < curmin){ curmin = vv; minslot = u; } }
        }
      }
    }
    __syncthreads();
  }
  if (g == 0){
    unsigned short* op = idxo + (size_t)(b*NN + pbase + pl)*KNN;
    #pragma unroll
    for (int j = 0; j < 20; ++j) op[j] = ti[j][t];
  }
}

// ---------- 3. weight prep f32->f16 [w2|w3|w4|w5] ----------
__global__ __launch_bounds__(256) void k_wprep(const float* __restrict__ W2, const float* __restrict__ W3,
    const float* __restrict__ W4, const float* __restrict__ W5, unsigned short* __restrict__ wh){
  int i = blockIdx.x*256 + threadIdx.x;
  float v;
  if (i < 4096) v = W2[i];
  else if (i < 12288) v = W3[i-4096];
  else if (i < 45056) v = W4[i-12288];
  else v = W5[i-45056];
  wh[i] = f2h(v);
}

// ---------- 4. conv1 ----------
__global__ __launch_bounds__(256) void k_conv1(const float* __restrict__ xt, const unsigned short* __restrict__ idx,
    const float* __restrict__ W1, unsigned short* __restrict__ y1){
  __shared__ float Wl[64*6];
  int t = threadIdx.x;
  for (int i = t; i < 384; i += 256) Wl[i] = W1[i];
  __syncthreads();
  int e = blockIdx.x*256 + t;
  int p = e / KNN;
  int b = p >> 11;
  int n = p & (NN-1);
  int nb = idx[e];
  const float4* xb = (const float4*)xt + (size_t)b*NN;
  float4 xnb = xb[nb], xcn = xb[n];
  unsigned short* yo = y1 + (size_t)e*64;
  #pragma unroll
  for (int o = 0; o < 64; o += 8){
    unsigned pk[4];
    #pragma unroll
    for (int q = 0; q < 4; ++q){
      const float* wa = &Wl[(o+2*q)*6];
      const float* wb = &Wl[(o+2*q+1)*6];
      float va = wa[0]*xnb.x + wa[1]*xnb.y + wa[2]*xnb.z + wa[3]*xcn.x + wa[4]*xcn.y + wa[5]*xcn.z;
      float vb = wb[0]*xnb.x + wb[1]*xnb.y + wb[2]*xnb.z + wb[3]*xcn.x + wb[4]*xcn.y + wb[5]*xcn.z;
      pk[q] = pkrtz(va, vb);
    }
    uint4 u; u.x = pk[0]; u.y = pk[1]; u.z = pk[2]; u.w = pk[3];
    *reinterpret_cast<uint4*>(yo + o) = u;
  }
}

// ---------- 5. stats for y1 (direct), 64-sharded ----------
__global__ __launch_bounds__(256) void k_stats1(const unsigned short* __restrict__ y, float* __restrict__ st){
  int t = threadIdx.x;
  int c = t & 63, ro = t >> 6;
  float s = 0.f, q = 0.f;
  for (int rb = blockIdx.x; rb < NEDGE/4; rb += gridDim.x){
    float v = h2f(y[(size_t)(rb*4 + ro)*64 + c]);
    s += v; q += v*v;
  }
  __shared__ float red[256];
  red[t] = s; __syncthreads();
  if (t < 64){ for (int g = 1; g < 4; ++g) s += red[t + g*64]; }
  __syncthreads(); red[t] = q; __syncthreads();
  if (t < 64){
    for (int g = 1; g < 4; ++g) q += red[t + g*64];
    int shard = blockIdx.x & 63;
    atomicAdd(&st[c*64 + shard], s);
    atomicAdd(&st[64*64 + c*64 + shard], q);
  }
}

// ---------- 5b. stats for y5 (slabbed [8][NPOS][64] f16) ----------
__global__ __launch_bounds__(256) void k_stats512(const unsigned short* __restrict__ y, float* __restrict__ st){
  int t = threadIdx.x;
  int slab = t >> 5, cc0 = (t & 31)*2;
  int c0 = slab*64 + cc0;
  const unsigned short* yb = y + (size_t)slab*NPOS*64 + cc0;
  float s0=0.f,q0=0.f,s1=0.f,q1=0.f;
  for (int rw = blockIdx.x; rw < NPOS; rw += gridDim.x){
    unsigned u = *reinterpret_cast<const unsigned*>(yb + (size_t)rw*64);
    float v0 = h2f((unsigned short)(u & 0xffffu)), v1 = h2f((unsigned short)(u >> 16));
    s0 += v0; q0 += v0*v0; s1 += v1; q1 += v1*v1;
  }
  int shard = blockIdx.x & 63;
  atomicAdd(&st[(size_t)c0*64 + shard], s0);
  atomicAdd(&st[(size_t)(512 + c0)*64 + shard], q0);
  atomicAdd(&st[(size_t)(c0+1)*64 + shard], s1);
  atomicAdd(&st[(size_t)(512 + c0+1)*64 + shard], q1);
}

// ---------- 6. finalize BN from sharded stats -> ac f32 + aH f16 ----------
__global__ void k_fin(const float* __restrict__ st, const float* __restrict__ gw, const float* __restrict__ bw,
                      float* __restrict__ act, unsigned short* __restrict__ actH, int C, float inv_n){
  int c = threadIdx.x;
  if (c >= C) return;
  float s = 0.f, q = 0.f;
  for (int i = 0; i < 64; ++i){ s += st[c*64 + i]; q += st[(size_t)C*64 + c*64 + i]; }
  float mean = s*inv_n;
  float var = q*inv_n - mean*mean;
  float sc = gw[c] * rsqrtf(var + 1e-5f);
  float sh = bw[c] - mean*sc;
  act[2*c] = sc; act[2*c+1] = sh;
  actH[c] = f2h(sc); actH[C + c] = f2h(sh);
}

// ---------- 7. layer-1 max pool ----------
__global__ __launch_bounds__(256) void k_max64(const unsigned short* __restrict__ y, const float* __restrict__ actp,
    unsigned short* __restrict__ xc, int xcoff){
  int gidx = blockIdx.x*256 + threadIdx.x;
  int q = gidx >> 5, cp = gidx & 31;
  int c = cp*2;
  float sc0 = actp[2*c],   sh0 = actp[2*c+1];
  float sc1 = actp[2*c+2], sh1 = actp[2*c+3];
  const unsigned* base = reinterpret_cast<const unsigned*>(y + (size_t)q*KNN*64 + c);
  float m0 = 0.f, m1 = 0.f;
  #pragma unroll
  for (int j = 0; j < KNN; ++j){
    unsigned v = base[(size_t)j*32];
    m0 = fmaxf(m0, sc0*h2f((unsigned short)(v & 0xffffu)) + sh0);
    m1 = fmaxf(m1, sc1*h2f((unsigned short)(v >> 16)) + sh1);
  }
  *reinterpret_cast<unsigned*>(xc + (size_t)q*512 + xcoff + c) = pkrtz(m0, m1);
}

// ---------- 8. Gram: G = sum_e a_e a_e^T (+colsum), transposed LDS staging ----------
// chunk = 64 edges. T[C][68] channel-major: frag read = 2x ds_read_b64 (8 edges, fixed ch).
// staging writes (scalar b16) are bank-conflict-free at stride 68 (8 rows = +16 banks).
template<int C, bool FOLD>
__global__ __launch_bounds__(256, 3) void k_gram(const unsigned short* __restrict__ inA,
    const unsigned short* __restrict__ inB, const unsigned short* __restrict__ aH,
    float* __restrict__ G, float* __restrict__ cs, int nchunks){
  constexpr int NFR = C/16;          // 4 (C=64) or 8 (C=128)
  constexpr int RI  = NFR/4;         // 1 or 2 row-blocks per wave
  constexpr int ST  = 68;
  __shared__ unsigned short T[C][ST];
  int t = threadIdx.x, lane = t & 63, w = t >> 6, g = lane >> 4, r = lane & 15;
  int se = t & 31;                   // staging edge within 32-edge pass
  int scg = t >> 5;                  // staging channel-group (0..7)
  const f16x8 zf = (f16x8)(_Float16)0.f;
  f16x8 fs, fh;
  if constexpr (FOLD){
    fs = *reinterpret_cast<const f16x8*>(aH + scg*8);
    fh = *reinterpret_cast<const f16x8*>(aH + C + scg*8);
  }
  f32x4 acc[RI][NFR];
  #pragma unroll
  for (int i = 0; i < RI; ++i)
    #pragma unroll
    for (int j = 0; j < NFR; ++j) acc[i][j] = 0.f;
  float csf[NFR] = {};
  for (int ch = blockIdx.x; ch < nchunks; ch += gridDim.x){
    size_t e0 = (size_t)ch*64;
    __syncthreads();     // previous chunk's reads done before overwrite
    #pragma unroll
    for (int ep = 0; ep < 2; ++ep){
      int e = ep*32 + se;
      f16x8 v = *reinterpret_cast<const f16x8*>(inA + (e0 + e)*64 + scg*8);
      if constexpr (FOLD) v = __builtin_elementwise_max(v*fs + fh, zf);
      #pragma unroll
      for (int j = 0; j < 8; ++j){ H16 x; x.h = v[j]; T[scg*8 + j][e] = x.u; }
      if constexpr (C == 128){
        f16x8 v1 = *reinterpret_cast<const f16x8*>(inB + (e0 + e)*64 + scg*8);
        #pragma unroll
        for (int j = 0; j < 8; ++j){ H16 x; x.h = v1[j]; T[64 + scg*8 + j][e] = x.u; }
      }
    }
    __syncthreads();
    #pragma unroll
    for (int ks = 0; ks < 2; ++ks){
      f16x8 fr[NFR];
      #pragma unroll
      for (int f = 0; f < NFR; ++f){
        const unsigned short* rp = &T[16*f + r][ks*32 + g*8];
        f16x4 lo = *reinterpret_cast<const f16x4*>(rp);
        f16x4 hi = *reinterpret_cast<const f16x4*>(rp + 4);
        f16x8 fv;
        fv[0]=lo[0]; fv[1]=lo[1]; fv[2]=lo[2]; fv[3]=lo[3];
        fv[4]=hi[0]; fv[5]=hi[1]; fv[6]=hi[2]; fv[7]=hi[3];
        fr[f] = fv;
      }
      if (w == 0){
        #pragma unroll
        for (int f = 0; f < NFR; ++f)
          #pragma unroll
          for (int jj = 0; jj < 8; ++jj) csf[f] += (float)fr[f][jj];
      }
      #pragma unroll
      for (int i = 0; i < RI; ++i)
        #pragma unroll
        for (int j = 0; j < NFR; ++j)
          acc[i][j] = __builtin_amdgcn_mfma_f32_16x16x32_f16(fr[RI*w + i], fr[j], acc[i][j], 0, 0, 0);
    }
  }
  #pragma unroll
  for (int i = 0; i < RI; ++i){
    int gr = 16*(RI*w + i) + 4*g;
    #pragma unroll
    for (int j = 0; j < NFR; ++j)
      #pragma unroll
      for (int p = 0; p < 4; ++p)
        atomicAdd(&G[(size_t)(gr + p)*C + 16*j + r], acc[i][j][p]);
  }
  if (w == 0){
    #pragma unroll
    for (int f = 0; f < NFR; ++f){
      float v = csf[f];
      v += __shfl_xor(v, 16);
      v += __shfl_xor(v, 32);
      if (lane < 16) atomicAdd(&cs[16*f + lane], v);
    }
  }
}

// ---------- 9. BN stats of NEXT layer from Gram + weights (linearity) ----------
template<int CIN, int COUT>
__global__ void k_fing(const float* __restrict__ G, const float* __restrict__ cs,
    const unsigned short* __restrict__ whp, const float* __restrict__ gw, const float* __restrict__ bw,
    float* __restrict__ ac, unsigned short* __restrict__ aH, float inv_n){
  __shared__ float red[CIN], red2[CIN];
  int o = blockIdx.x, i = threadIdx.x;
  float wi = h2f(whp[(size_t)o*CIN + i]);
  float v = 0.f;
  for (int j = 0; j < CIN; ++j) v += G[(size_t)i*CIN + j] * h2f(whp[(size_t)o*CIN + j]);
  red[i] = wi*v; red2[i] = wi*cs[i];
  __syncthreads();
  for (int s = CIN/2; s > 0; s >>= 1){
    if (i < s){ red[i] += red[i+s]; red2[i] += red2[i+s]; }
    __syncthreads();
  }
  if (i == 0){
    float mean = red2[0]*inv_n;
    float var = red[0]*inv_n - mean*mean;
    float sc = gw[o]*rsqrtf(var + 1e-5f);
    float sh = bw[o] - mean*sc;
    ac[2*o] = sc; ac[2*o+1] = sh;
    aH[o] = f2h(sc); aH[COUT + o] = f2h(sh);
  }
}

// ---------- 10. conv: post-act output, optional input fold / store / window max-pool ----------
template<int CIN, int COUT, bool INFOLD, bool OUTACT, bool POOL, bool STORE>
__global__ __launch_bounds__(256, 3) void k_cpost(
    const unsigned short* __restrict__ inA, const unsigned short* __restrict__ inB,
    const unsigned short* __restrict__ Wh, const unsigned short* __restrict__ aHin,
    const float* __restrict__ acOut, unsigned short* __restrict__ out, size_t slabStride,
    unsigned short* __restrict__ xc, int coff, int NT){
  constexpr int NKC = CIN/32;
  constexpr int NO = COUT/64;
  constexpr int LIM = POOL ? 20 : 32;
  constexpr int RS = (CIN == 128) ? 64 : CIN;
  __shared__ unsigned short Tw[4][32][68];
  int t = threadIdx.x, lane = t & 63, w = t >> 6, g = lane >> 4, r16 = lane & 15;
  const f16x8 zf = (f16x8)(_Float16)0.f;
  f16x8 fs[INFOLD ? NKC : 1], fh[INFOLD ? NKC : 1];
  if constexpr (INFOLD){
    #pragma unroll
    for (int kc = 0; kc < NKC; ++kc){
      fs[kc] = *reinterpret_cast<const f16x8*>(aHin + kc*32 + g*8);
      fh[kc] = *reinterpret_cast<const f16x8*>(aHin + CIN + kc*32 + g*8);
    }
  }
  int wid = blockIdx.x*4 + w;
  int nw = gridDim.x*4;
  for (int task = wid; task < NT; task += nw){
    int p0 = task * (POOL ? 20 : 32);
    int ra = p0 + r16;
    int rb = POOL ? (p0 + 16 + (r16 < 4 ? r16 : 3)) : (p0 + 16 + r16);
    f16x8 A0[(CIN <= 128) ? NKC : 1], A1[(CIN <= 128) ? NKC : 1];
    if constexpr (CIN <= 128){
      #pragma unroll
      for (int kc = 0; kc < NKC; ++kc){
        const unsigned short* ab; int kl;
        if constexpr (CIN == 128){ ab = (kc < NKC/2) ? inA : inB; kl = kc & (NKC/2 - 1); }
        else { ab = inA; kl = kc; }
        f16x8 a0 = *reinterpret_cast<const f16x8*>(ab + (size_t)ra*RS + kl*32 + g*8);
        f16x8 a1 = *reinterpret_cast<const f16x8*>(ab + (size_t)rb*RS + kl*32 + g*8);
        if constexpr (INFOLD){
          a0 = __builtin_elementwise_max(a0*fs[kc] + fh[kc], zf);
          a1 = __builtin_elementwise_max(a1*fs[kc] + fh[kc], zf);
        }
        A0[kc] = a0; A1[kc] = a1;
      }
    }
    #pragma unroll 1
    for (int o = 0; o < NO; ++o){
      f32x4 acc[2][4];
      #pragma unroll
      for (int m = 0; m < 2; ++m)
        #pragma unroll
        for (int n = 0; n < 4; ++n) acc[m][n] = 0.f;
      #pragma unroll 4
      for (int kc = 0; kc < NKC; ++kc){
        f16x8 a0, a1;
        if constexpr (CIN <= 128){ a0 = A0[kc]; a1 = A1[kc]; }
        else {
          a0 = *reinterpret_cast<const f16x8*>(inA + (size_t)ra*CIN + kc*32 + g*8);
          a1 = *reinterpret_cast<const f16x8*>(inA + (size_t)rb*CIN + kc*32 + g*8);
        }
        #pragma unroll
        for (int n = 0; n < 4; ++n){
          f16x8 bv = *reinterpret_cast<const f16x8*>(Wh + (size_t)(o*64 + 16*n + r16)*CIN + kc*32 + g*8);
          acc[0][n] = __builtin_amdgcn_mfma_f32_16x16x32_f16(bv, a0, acc[0][n], 0, 0, 0);
          acc[1][n] = __builtin_amdgcn_mfma_f32_16x16x32_f16(bv, a1, acc[1][n], 0, 0, 0);
        }
      }
      if constexpr (OUTACT){
        #pragma unroll
        for (int n = 0; n < 4; ++n){
          const float4* ap = reinterpret_cast<const float4*>(acOut + 2*(o*64 + 16*n + 4*g));
          float4 q0 = ap[0], q1 = ap[1];
          #pragma unroll
          for (int m = 0; m < 2; ++m){
            acc[m][n][0] = fmaxf(0.f, acc[m][n][0]*q0.x + q0.y);
            acc[m][n][1] = fmaxf(0.f, acc[m][n][1]*q0.z + q0.w);
            acc[m][n][2] = fmaxf(0.f, acc[m][n][2]*q1.x + q1.y);
            acc[m][n][3] = fmaxf(0.f, acc[m][n][3]*q1.z + q1.w);
          }
        }
      }
      if constexpr (STORE){
        #pragma unroll
        for (int m = 0; m < 2; ++m)
          #pragma unroll
          for (int n = 0; n < 4; ++n){
            uint2 d;
            d.x = pkrtz(acc[m][n][0], acc[m][n][1]);
            d.y = pkrtz(acc[m][n][2], acc[m][n][3]);
            *reinterpret_cast<uint2*>(&Tw[w][16*m + r16][16*n + 4*g]) = d;
          }
        int pos = lane >> 1, chh = (lane & 1) * 32;
        if (pos < LIM){
          const unsigned short* rp = &Tw[w][pos][chh];
          uint2 d0 = *reinterpret_cast<const uint2*>(rp);
          uint2 d1 = *reinterpret_cast<const uint2*>(rp + 4);
          uint2 d2 = *reinterpret_cast<const uint2*>(rp + 8);
          uint2 d3 = *reinterpret_cast<const uint2*>(rp + 12);
          uint2 d4 = *reinterpret_cast<const uint2*>(rp + 16);
          uint2 d5 = *reinterpret_cast<const uint2*>(rp + 20);
          uint2 d6 = *reinterpret_cast<const uint2*>(rp + 24);
          uint2 d7 = *reinterpret_cast<const uint2*>(rp + 28);
          uint4* op = reinterpret_cast<uint4*>(out + (size_t)o*slabStride + ((size_t)(p0 + pos))*64 + chh);
          op[0] = make_uint4(d0.x, d0.y, d1.x, d1.y);
          op[1] = make_uint4(d2.x, d2.y, d3.x, d3.y);
          op[2] = make_uint4(d4.x, d4.y, d5.x, d5.y);
          op[3] = make_uint4(d6.x, d6.y, d7.x, d7.y);
        }
      }
      if constexpr (POOL){
        #pragma unroll
        for (int n = 0; n < 4; ++n){
          float vr[4];
          #pragma unroll
          for (int r = 0; r < 4; ++r){
            float v = fmaxf(acc[0][n][r], acc[1][n][r]);
            v = fmaxf(v, __shfl_xor(v, 1));
            v = fmaxf(v, __shfl_xor(v, 2));
            v = fmaxf(v, __shfl_xor(v, 4));
            v = fmaxf(v, __shfl_xor(v, 8));
            vr[r] = v;
          }
          if (r16 == 0){
            uint2 u;
            u.x = pkrtz(vr[0], vr[1]);
            u.y = pkrtz(vr[2], vr[3]);
            *reinterpret_cast<uint2*>(xc + (size_t)task*512 + coff + o*64 + 16*n + 4*g) = u;
          }
        }
      }
    }
  }
}

// ---------- 11. final: bn5+relu on y5 slabs [8][NPOS][64] f16 -> out [b][512][n] f32 ----------
__global__ void k_out(const unsigned short* __restrict__ y5, const float* __restrict__ actp, float* __restrict__ out){
  __shared__ float tile[32][33];
  int b = blockIdx.z, n0 = blockIdx.x*32, c0 = blockIdx.y*32;
  int lx = threadIdx.x, ly = threadIdx.y;
  int slab = c0 >> 6, cin = (c0 & 63) + lx;
  float sc = actp[2*(c0+lx)], sh = actp[2*(c0+lx)+1];
  const unsigned short* yb = y5 + (size_t)slab*NPOS*64 + (size_t)(b*NN + n0)*64 + cin;
  for (int yy = ly; yy < 32; yy += 8)
    tile[yy][lx] = fmaxf(0.f, sc*h2f(yb[(size_t)yy*64]) + sh);
  __syncthreads();
  for (int yy = ly; yy < 32; yy += 8)
    out[((size_t)(b*512 + c0 + yy))*NN + n0 + lx] = tile[lx][yy];
}

// ---------- launch ----------
extern "C" void kernel_launch(void* const* d_in, const int* in_sizes, int n_in,
                              void* d_out, int out_size, void* d_ws, size_t ws_size,
                              hipStream_t stream){
  const float* pts = (const float*)d_in[0];
  const float* W1 = (const float*)d_in[1];
  const float* W2 = (const float*)d_in[2];
  const float* W3 = (const float*)d_in[3];
  const float* W4 = (const float*)d_in[4];
  const float* W5 = (const float*)d_in[5];
  const float* g1 = (const float*)d_in[6];  const float* b1 = (const float*)d_in[7];
  const float* g2 = (const float*)d_in[8];  const float* b2 = (const float*)d_in[9];
  const float* g3 = (const float*)d_in[10]; const float* b3 = (const float*)d_in[11];
  const float* g4 = (const float*)d_in[12]; const float* b4 = (const float*)d_in[13];
  const float* g5 = (const float*)d_in[14]; const float* b5 = (const float*)d_in[15];

  char* ws = (char*)d_ws;
  float*          xt    = (float*)(ws + 0);                      // 256 KB
  unsigned short* idxu  = (unsigned short*)(ws + 262144);        // 640 KB
  float*          stats = (float*)(ws + 917504);                 // 288 KB  (st1 + st5)
  float*          gbuf  = (float*)(ws + 1212416);                // ~100 KB (G1,G2,G3,cs1,cs2,cs3)
  float*          acts  = (float*)(ws + 1314816);                // 8 KB f32
  unsigned short* actsH = (unsigned short*)(ws + 1323008);       // 4 KB f16
  unsigned short* wh    = (unsigned short*)(ws + 1327104);       // 600 KB f16 weights
  // big buffers with overlays:
  unsigned short* y1  = (unsigned short*)(ws + 2097152);         // 40 MiB
  unsigned short* y3a = (unsigned short*)(ws + 2097152);         //   (overlays dead y1)
  unsigned short* y2p = (unsigned short*)(ws + 44040192);        // 40 MiB
  unsigned short* y5  = (unsigned short*)(ws + 44040192);        //   (overlays dead y2p, 16 MiB)
  unsigned short* y3b = (unsigned short*)(ws + 85983232);        // 40 MiB
  unsigned short* xc  = (unsigned short*)(ws + 127926272);       // 16 MiB -> end ~138 MiB
  float* out = (float*)d_out;

  unsigned short* w2h = wh;
  unsigned short* w3h = wh + 4096;
  unsigned short* w4h = wh + 12288;
  unsigned short* w5h = wh + 45056;

  float* st1 = stats;
  float* st5 = stats + 8192;
  float* G1 = gbuf, *G2 = gbuf + 4096, *G3 = gbuf + 8192;
  float* cs1 = gbuf + 24576, *cs2 = gbuf + 24640, *cs3 = gbuf + 24704;
  float* ac1 = acts + 0,  *ac2 = acts + 128, *ac3 = acts + 256, *ac4 = acts + 512, *ac5 = acts + 1024;
  unsigned short* aH1 = actsH + 0,   *aH2 = actsH + 128, *aH3 = actsH + 256,
                * aH4 = actsH + 512, *aH5 = actsH + 1024;
  const size_t y3str = (size_t)(85983232 - 2097152) / 2;

  hipMemsetAsync(stats, 0, 294912, stream);
  hipMemsetAsync(gbuf, 0, 102400, stream);
  k_wprep<<<1200, 256, 0, stream>>>(W2, W3, W4, W5, wh);
  k_demean<<<24, 256, 0, stream>>>(pts, xt);
  k_knn<<<512, 256, 0, stream>>>(xt, idxu);
  k_conv1<<<NEDGE/256, 256, 0, stream>>>(xt, idxu, W1, y1);
  k_stats1<<<256, 256, 0, stream>>>(y1, st1);
  k_fin<<<1, 64, 0, stream>>>(st1, g1, b1, ac1, aH1, 64, 1.f/NEDGE);
  k_max64<<<NPOS*32/256, 256, 0, stream>>>(y1, ac1, xc, 0);
  k_gram<64, true><<<1024, 256, 0, stream>>>(y1, nullptr, aH1, G1, cs1, NEDGE/64);
  k_fing<64, 64><<<64, 64, 0, stream>>>(G1, cs1, w2h, g2, b2, ac2, aH2, 1.f/NEDGE);
  k_cpost<64, 64, true, true, true, true><<<1024, 256, 0, stream>>>(
      y1, nullptr, w2h, aH1, ac2, y2p, 0, xc, 64, NPOS);
  k_gram<64, false><<<1024, 256, 0, stream>>>(y2p, nullptr, nullptr, G2, cs2, NEDGE/64);
  k_fing<64, 128><<<128, 64, 0, stream>>>(G2, cs2, w3h, g3, b3, ac3, aH3, 1.f/NEDGE);
  k_cpost<64, 128, false, true, true, true><<<1024, 256, 0, stream>>>(
      y2p, nullptr, w3h, nullptr, ac3, y3a, y3str, xc, 128, NPOS);
  k_gram<128, false><<<1024, 256, 0, stream>>>(y3a, y3b, nullptr, G3, cs3, NEDGE/64);
  k_fing<128, 256><<<256, 128, 0, stream>>>(G3, cs3, w4h, g4, b4, ac4, aH4, 1.f/NEDGE);
  k_cpost<128, 256, false, true, true, false><<<1024, 256, 0, stream>>>(
      y3a, y3b, w4h, nullptr, ac4, nullptr, 0, xc, 256, NPOS);
  k_cpost<512, 512, false, false, false, true><<<128, 256, 0, stream>>>(
      xc, nullptr, w5h, nullptr, nullptr, y5, (size_t)NPOS*64, nullptr, 0, NPOS/32);
  k_stats512<<<256, 256, 0, stream>>>(y5, st5);
  k_fin<<<1, 512, 0, stream>>>(st5, g5, b5, ac5, aH5, 512, 1.f/NPOS);
  k_out<<<dim3(NN/32, 16, BB), dim3(32, 8), 0, stream>>>(y5, ac5, out);
}